// Round 1
// baseline (884.878 us; speedup 1.0000x reference)
//
#include <hip/hip_runtime.h>

#define BB 2048
#define TT 1024
#define CC 9
#define HH 36

// One wave (64 lanes) per batch element. Lane j < 36 owns hidden index j and
// computes its r/z/n gates as full-length dot products (weights in VGPRs).
// h (36 floats) is replicated in every lane's registers and refreshed each
// timestep through a tiny LDS broadcast buffer.
__global__ __launch_bounds__(64) void gru_kernel(
    const float* __restrict__ x,      // (B,T,C)
    const float* __restrict__ w_ih,   // (3H,C)
    const float* __restrict__ w_hh,   // (3H,H)
    const float* __restrict__ b_ih,   // (3H)
    const float* __restrict__ b_hh,   // (3H)
    const float* __restrict__ w_head, // (1,H)
    const float* __restrict__ b_head, // (1)
    float* __restrict__ out)          // (B,1)
{
    const int b = blockIdx.x;
    const int j = threadIdx.x;        // lane; active gate work for j < 36

    __shared__ float hbuf[HH];

    // Per-lane weights (only meaningful for j < 36; other lanes run masked-off
    // garbage that never escapes).
    float wr_h[HH], wz_h[HH], wn_h[HH];
    float wr_i[CC], wz_i[CC], wn_i[CC];
    float br = 0.f, bz = 0.f, bn_i = 0.f, bn_h = 0.f;
    if (j < HH) {
#pragma unroll
        for (int k = 0; k < HH; ++k) {
            wr_h[k] = w_hh[(size_t)(j) * HH + k];
            wz_h[k] = w_hh[(size_t)(HH + j) * HH + k];
            wn_h[k] = w_hh[(size_t)(2 * HH + j) * HH + k];
        }
#pragma unroll
        for (int c = 0; c < CC; ++c) {
            wr_i[c] = w_ih[(size_t)(j) * CC + c];
            wz_i[c] = w_ih[(size_t)(HH + j) * CC + c];
            wn_i[c] = w_ih[(size_t)(2 * HH + j) * CC + c];
        }
        br   = b_ih[j]          + b_hh[j];
        bz   = b_ih[HH + j]     + b_hh[HH + j];
        bn_i = b_ih[2 * HH + j];
        bn_h = b_hh[2 * HH + j];
    }

    float h[HH];
#pragma unroll
    for (int k = 0; k < HH; ++k) h[k] = 0.f;
    float h_own = 0.f;

    const float* xp = x + (size_t)b * TT * CC;

    // Prefetch x for t=0 (wave-uniform address -> scalar loads).
    float xv[CC];
#pragma unroll
    for (int c = 0; c < CC; ++c) xv[c] = xp[c];

    for (int t = 0; t < TT; ++t) {
        // Prefetch next timestep's x one step ahead.
        float xn[CC];
        if (t + 1 < TT) {
            const float* nxt = xp + CC;
#pragma unroll
            for (int c = 0; c < CC; ++c) xn[c] = nxt[c];
        }

        float sr = br, sz = bz, sn = bn_i, gn = bn_h;
#pragma unroll
        for (int c = 0; c < CC; ++c) {
            sr += wr_i[c] * xv[c];
            sz += wz_i[c] * xv[c];
            sn += wn_i[c] * xv[c];
        }
#pragma unroll
        for (int k = 0; k < HH; ++k) {
            sr += wr_h[k] * h[k];
            sz += wz_h[k] * h[k];
            gn += wn_h[k] * h[k];
        }

        // sigmoid / tanh via fast exp + fast rcp (fp32, well within tolerance)
        float er = __expf(-sr);
        float r  = __builtin_amdgcn_rcpf(1.f + er);
        float ez = __expf(-sz);
        float z  = __builtin_amdgcn_rcpf(1.f + ez);
        float a  = sn + r * gn;
        float ea = __expf(2.f * a);
        float n  = 1.f - 2.f * __builtin_amdgcn_rcpf(ea + 1.f);

        h_own = z * (h_own - n) + n;

        __syncthreads();
        if (j < HH) hbuf[j] = h_own;
        __syncthreads();
#pragma unroll
        for (int k = 0; k < HH; ++k) h[k] = hbuf[k];

#pragma unroll
        for (int c = 0; c < CC; ++c) xv[c] = xn[c];
        xp += CC;
    }

    // Head: out[b] = sum_j h_last[j] * w_head[j] + b_head
    float v = (j < HH) ? h_own * w_head[j] : 0.f;
#pragma unroll
    for (int off = 32; off; off >>= 1) v += __shfl_down(v, off);
    if (j == 0) out[b] = v + b_head[0];
}

extern "C" void kernel_launch(void* const* d_in, const int* in_sizes, int n_in,
                              void* d_out, int out_size, void* d_ws, size_t ws_size,
                              hipStream_t stream) {
    const float* x      = (const float*)d_in[0];
    const float* w_ih   = (const float*)d_in[1];
    const float* w_hh   = (const float*)d_in[2];
    const float* b_ih   = (const float*)d_in[3];
    const float* b_hh   = (const float*)d_in[4];
    const float* w_head = (const float*)d_in[5];
    const float* b_head = (const float*)d_in[6];
    float* out = (float*)d_out;

    gru_kernel<<<BB, 64, 0, stream>>>(x, w_ih, w_hh, b_ih, b_hh,
                                      w_head, b_head, out);
}

// Round 2
// 535.687 us; speedup vs baseline: 1.6519x; 1.6519x over previous
//
#include <hip/hip_runtime.h>

typedef float v2f __attribute__((ext_vector_type(2)));

#define BB 2048
#define TT 1024
#define CC 9
#define HH 36

// One wave (64 lanes) per batch element. Lane j < 36 owns hidden index j and
// computes its r/z/n gates as full dot products. All weights are held in
// VGPRs as float2 pairs so the inner loop is pure v_pk_fma_f32 (no per-step
// weight reloads). __launch_bounds__(64,2) raises the VGPR budget to 256
// (2 waves/SIMD = exactly what grid 2048 provides on 1024 SIMDs).
__global__ __launch_bounds__(64, 2) void gru_kernel(
    const float* __restrict__ x,      // (B,T,C)
    const float* __restrict__ w_ih,   // (3H,C)
    const float* __restrict__ w_hh,   // (3H,H)
    const float* __restrict__ b_ih,   // (3H)
    const float* __restrict__ b_hh,   // (3H)
    const float* __restrict__ w_head, // (1,H)
    const float* __restrict__ b_head, // (1)
    float* __restrict__ out)          // (B,1)
{
    const int b = blockIdx.x;
    const int j = threadIdx.x;

    __shared__ __align__(16) float hbuf[HH];

    // Packed per-lane weights (lanes >= 36 hold garbage that never escapes).
    v2f wr[18], wz[18], wn[18];   // w_hh rows (36 floats -> 18 pairs each)
    v2f wri[5], wzi[5], wni[5];   // w_ih rows (9 floats -> 4.5 pairs, padded)
    float br = 0.f, bz = 0.f, bni = 0.f, bnh = 0.f, whead = 0.f;
    if (j < HH) {
        const float* pr = w_hh + (size_t)j * HH;            // rows are 144B -> 8B aligned
        const float* pz = w_hh + (size_t)(HH + j) * HH;
        const float* pn = w_hh + (size_t)(2 * HH + j) * HH;
#pragma unroll
        for (int k = 0; k < 18; ++k) {
            wr[k] = *(const v2f*)(pr + 2 * k);
            wz[k] = *(const v2f*)(pz + 2 * k);
            wn[k] = *(const v2f*)(pn + 2 * k);
        }
        const float* qr = w_ih + (size_t)j * CC;            // rows 36B -> only 4B aligned: scalar assemble
        const float* qz = w_ih + (size_t)(HH + j) * CC;
        const float* qn = w_ih + (size_t)(2 * HH + j) * CC;
#pragma unroll
        for (int p = 0; p < 4; ++p) {
            wri[p] = (v2f){qr[2 * p], qr[2 * p + 1]};
            wzi[p] = (v2f){qz[2 * p], qz[2 * p + 1]};
            wni[p] = (v2f){qn[2 * p], qn[2 * p + 1]};
        }
        wri[4] = (v2f){qr[8], 0.f};
        wzi[4] = (v2f){qz[8], 0.f};
        wni[4] = (v2f){qn[8], 0.f};
        br  = b_ih[j] + b_hh[j];
        bz  = b_ih[HH + j] + b_hh[HH + j];
        bni = b_ih[2 * HH + j];
        bnh = b_hh[2 * HH + j];
        whead = w_head[j];
    }

    v2f h2[18];
#pragma unroll
    for (int k = 0; k < 18; ++k) h2[k] = (v2f){0.f, 0.f};
    float h_own = 0.f;

    const float* xp = x + (size_t)b * TT * CC;

    // x for t=0 (wave-uniform address -> scalar loads), packed into pairs.
    v2f xv[5];
    xv[0] = (v2f){xp[0], xp[1]};
    xv[1] = (v2f){xp[2], xp[3]};
    xv[2] = (v2f){xp[4], xp[5]};
    xv[3] = (v2f){xp[6], xp[7]};
    xv[4] = (v2f){xp[8], 0.f};

    for (int t = 0; t < TT; ++t) {
        // Prefetch next step's x.
        v2f xn[5];
        if (t + 1 < TT) {
            const float* nx = xp + CC;
            xn[0] = (v2f){nx[0], nx[1]};
            xn[1] = (v2f){nx[2], nx[3]};
            xn[2] = (v2f){nx[4], nx[5]};
            xn[3] = (v2f){nx[6], nx[7]};
            xn[4] = (v2f){nx[8], 0.f};
        } else {
#pragma unroll
            for (int p = 0; p < 5; ++p) xn[p] = (v2f){0.f, 0.f};
        }

        v2f ar = (v2f){br, 0.f};
        v2f az = (v2f){bz, 0.f};
        v2f an = (v2f){bni, 0.f};
        v2f ag = (v2f){bnh, 0.f};
#pragma unroll
        for (int p = 0; p < 5; ++p) {
            ar = __builtin_elementwise_fma(wri[p], xv[p], ar);
            az = __builtin_elementwise_fma(wzi[p], xv[p], az);
            an = __builtin_elementwise_fma(wni[p], xv[p], an);
        }
#pragma unroll
        for (int k = 0; k < 18; ++k) {
            ar = __builtin_elementwise_fma(wr[k], h2[k], ar);
            az = __builtin_elementwise_fma(wz[k], h2[k], az);
            ag = __builtin_elementwise_fma(wn[k], h2[k], ag);
        }
        float sr = ar.x + ar.y;
        float sz = az.x + az.y;
        float sn = an.x + an.y;
        float gn = ag.x + ag.y;

        float r = __builtin_amdgcn_rcpf(1.f + __expf(-sr));
        float z = __builtin_amdgcn_rcpf(1.f + __expf(-sz));
        float a = sn + r * gn;
        float n = 1.f - 2.f * __builtin_amdgcn_rcpf(__expf(2.f * a) + 1.f);
        h_own = z * (h_own - n) + n;

        __syncthreads();
        if (j < HH) hbuf[j] = h_own;
        __syncthreads();
#pragma unroll
        for (int q = 0; q < 9; ++q) {
            float4 tq = *(const float4*)&hbuf[4 * q];
            h2[2 * q]     = (v2f){tq.x, tq.y};
            h2[2 * q + 1] = (v2f){tq.z, tq.w};
        }

#pragma unroll
        for (int p = 0; p < 5; ++p) xv[p] = xn[p];
        xp += CC;
    }

    float v = (j < HH) ? h_own * whead : 0.f;
#pragma unroll
    for (int off = 32; off; off >>= 1) v += __shfl_down(v, off);
    if (j == 0) out[b] = v + b_head[0];
}

extern "C" void kernel_launch(void* const* d_in, const int* in_sizes, int n_in,
                              void* d_out, int out_size, void* d_ws, size_t ws_size,
                              hipStream_t stream) {
    const float* x      = (const float*)d_in[0];
    const float* w_ih   = (const float*)d_in[1];
    const float* w_hh   = (const float*)d_in[2];
    const float* b_ih   = (const float*)d_in[3];
    const float* b_hh   = (const float*)d_in[4];
    const float* w_head = (const float*)d_in[5];
    const float* b_head = (const float*)d_in[6];
    float* out = (float*)d_out;

    gru_kernel<<<BB, 64, 0, stream>>>(x, w_ih, w_hh, b_ih, b_hh,
                                      w_head, b_head, out);
}